// Round 1
// baseline (1164.214 us; speedup 1.0000x reference)
//
#include <hip/hip_runtime.h>

// LSTM char-RNN forward: batch=1024, T=512, UNITS=256, NUM_CHARS=128.
// R9 = R8 (1094us) + same-XCD L2 fast path for the h-exchange.
//
// R8 counters showed WRITE_SIZE 524800 KB == exactly the 512 steps x 1MB of
// hx2 publishes, and FETCH_SIZE ~268MB ~= the polls: the agent-scope
// atomics are serviced at the HBM/IF coherence point, so each step pays a
// ~2500-3300 cycle store->visible->load round trip -- the dominant term of
// the 5130-cycle step. Sibling blocks (bid, bid+64) land on the same XCD
// under the bid%8 round-robin (64%8==0), sharing one L2. Fast path:
// producer ALSO stores the tagged u64 with a plain writeback store (stays
// in the shared L2); consumer polls that mirror with an L1-bypass (sc0)
// load -> ~200-400 cycle round trip. Placement is heuristic-only, so the
// fast spin is bounded and downgrades permanently (per-thread, 2 strikes)
// to R8's proven agent-scope path; cross-XCD the consumer's L2 caches a
// stale line forever, so failure is immediate+stable and costs a bounded
// one-time spin. Stale/poison/replay-leftover fast lines are harmless: use
// is gated on tag==t, and any word with tag==t holds the deterministic
// h(t) payload (same argument that already makes hx2 replay-proof in R8).
// Arithmetic identical to R8 -> same absmax (6.1e-5).

#define TSTEPS 512
#define UNITS  256
#define NCHAR  128
#define G4     1024
#define ZS     516   // zbuf row stride

typedef float    f32x4 __attribute__((ext_vector_type(4)));
typedef _Float16 f16x8 __attribute__((ext_vector_type(8)));

union FU { uint4 u4; f16x8 h8; _Float16 h[8]; };
union HP { unsigned int u; _Float16 f[2]; };

__device__ __forceinline__ float fast_rcp(float x) {
#if __has_builtin(__builtin_amdgcn_rcpf)
  return __builtin_amdgcn_rcpf(x);
#else
  return 1.0f / x;
#endif
}
__device__ __forceinline__ float sigm(float x)  { return fast_rcp(1.0f + __expf(-x)); }
__device__ __forceinline__ float tanhx(float x) { return 2.0f * fast_rcp(1.0f + __expf(-2.0f * x)) - 1.0f; }

// L1-bypass load: reads the shared per-XCD L2 copy (sc0 = bypass L0/L1,
// hit L2). This is the consumer side of the same-XCD fast exchange.
__device__ __forceinline__ unsigned long long ld_l2(const unsigned long long* p) {
  unsigned long long v;
  asm volatile("global_load_dwordx2 %0, %1, off sc0\n\ts_waitcnt vmcnt(0)"
               : "=v"(v) : "v"(p) : "memory");
  return v;
}

// ---- Prep: WhB = Wh fp16 B-fragment stream. idx=((cc*32+tile)*8+kk)*64+l.
__global__ void prep_whB(const float* __restrict__ Wh, uint4* __restrict__ WhB) {
  int idx = blockIdx.x * blockDim.x + threadIdx.x;    // 0..32767
  int l    = idx & 63;
  int kk   = (idx >> 6) & 7;
  int tile = (idx >> 9) & 31;
  int cc   = idx >> 14;
  int n    = tile * 16 + (l & 15);
  int gate = n & 3;
  int col  = gate * 256 + cc * 128 + (n >> 2);
  int kb   = kk * 32 + (l >> 4) * 8;
  FU p;
#pragma unroll
  for (int j = 0; j < 8; ++j)
    p.h[j] = (_Float16)Wh[(kb + j) * G4 + col];
  WhB[idx] = p.u4;
}

// ---- Prep: Wxbg[ch][u] = float4(i,f,g,o) = Wx[ch][gate*256+u] + b
__global__ void prep_wx(const float* __restrict__ Wx, const float* __restrict__ bias,
                        float4* __restrict__ Wxbg) {
  int idx = blockIdx.x * blockDim.x + threadIdx.x;    // 0..32767
  int u  = idx & (UNITS - 1);
  int ch = idx >> 8;
  const float* r = Wx + ch * G4;
  float4 o;
  o.x = r[0 * UNITS + u] + bias[0 * UNITS + u];
  o.y = r[1 * UNITS + u] + bias[1 * UNITS + u];
  o.z = r[2 * UNITS + u] + bias[2 * UNITS + u];
  o.w = r[3 * UNITS + u] + bias[3 * UNITS + u];
  Wxbg[idx] = o;
}

// A-frag LDS byte address for h element (row m, k).
__device__ __forceinline__ int afrag_addr(int k, int m) {
  return ((k >> 5) << 10) + (((((k >> 3) & 3) << 4) + m) << 4) + ((k & 7) << 1);
}

// ---- Main: 128 blocks x 1024 threads. (g = bid&63, c = bid>>6).
__global__ __launch_bounds__(1024) void lstm_mfma(
    const int* __restrict__ inp, const uint4* __restrict__ WhB,
    const float4* __restrict__ Wxbg, const float* __restrict__ Wd,
    const float* __restrict__ bd, float* __restrict__ out,
    unsigned long long* __restrict__ hx2, unsigned long long* __restrict__ fx2) {
  __shared__ __align__(16) uint4 hfrag[512];     // 8 KB: h_t A-frags (K=256)
  __shared__ float zbuf[16 * ZS];                // 33 KB
  __shared__ float lgts[16 * 132];               // 8.4 KB
  __shared__ float rmax[16], rsum[16];

  const int tid  = threadIdx.x;
  const int lane = tid & 63;
  const int wv   = tid >> 6;          // 0..15 == batch row within group
  const int bid  = blockIdx.x;
  const int g    = bid & 63;
  const int c    = bid >> 6;          // column half
  const int row0 = g * 16;

  // ---- Weight B-frags, own-half kk's in slots 0..3, sibling-half in 4..7.
  FU wf0[8], wf1[8];
#pragma unroll
  for (int kx = 0; kx < 8; ++kx) {
    int kk = (kx < 4) ? (c * 4 + kx) : ((1 - c) * 4 + (kx - 4));
    wf0[kx].u4 = WhB[((c * 32 + wv * 2)     * 8 + kk) * 64 + lane];
    wf1[kx].u4 = WhB[((c * 32 + wv * 2 + 1) * 8 + kk) * 64 + lane];
  }
#pragma unroll
  for (int kx = 0; kx < 8; ++kx) {
    asm volatile("" : "+v"(wf0[kx].u4.x), "+v"(wf0[kx].u4.y), "+v"(wf0[kx].u4.z), "+v"(wf0[kx].u4.w));
    asm volatile("" : "+v"(wf1[kx].u4.x), "+v"(wf1[kx].u4.y), "+v"(wf1[kx].u4.z), "+v"(wf1[kx].u4.w));
  }

  if (tid < 512) hfrag[tid] = uint4{0u, 0u, 0u, 0u};   // h_0 = 0
  float cst0 = 0.f, cst1 = 0.f;
  __syncthreads();
  const int kown = c * 4, ksib = (1 - c) * 4;
  const int cs   = 1 - c;

  bool fast_ok = true;   // same-XCD heuristic; self-correcting
  int  strikes = 0;
  HP   hpub; hpub.u = 0;

  for (int t = 0; t < TSTEPS; ++t) {
    int    ch  = inp[(row0 + wv) * TSTEPS + t];
    float4 xb0 = Wxbg[ch * 256 + c * 128 + lane];
    float4 xb1 = Wxbg[ch * 256 + c * 128 + 64 + lane];

    // ---- own-half K MFMA first (hides exchange latency); t=0: hfrag = 0
    f32x4 acc0 = {0.f, 0.f, 0.f, 0.f}, acc1 = {0.f, 0.f, 0.f, 0.f};
#pragma unroll
    for (int kx = 0; kx < 4; ++kx) {
      FU a; a.u4 = hfrag[(kown + kx) * 64 + lane];
      acc0 = __builtin_amdgcn_mfma_f32_16x16x32_f16(a.h8, wf0[kx].h8, acc0, 0, 0, 0);
      acc1 = __builtin_amdgcn_mfma_f32_16x16x32_f16(a.h8, wf1[kx].h8, acc1, 0, 0, 0);
    }

    if (t > 0) {
      // ---- fused detect+gather: poll own payload word until tag == t.
      // Fast: sc0 poll of the L2-resident mirror. Slow: R8 agent path.
      const int par = t & 1;
      const int off = ((par * 64 + g) * 2 + cs) * 1024 + tid;
      unsigned long long v = 0;
      bool got = false;
      if (fast_ok) {
        const unsigned long long* fsrc = fx2 + off;
        const int spins = (t == 1) ? 384 : 64;
        for (int s = 0; s < spins; ++s) {
          v = ld_l2(fsrc);
          if ((unsigned)(v >> 32) == (unsigned)t) { got = true; break; }
        }
        if (!got && ++strikes >= 2) fast_ok = false;
      }
      if (!got) {
        const unsigned long long* src = hx2 + off;
        long guard = 0;
        do {
          v = __hip_atomic_load(src, __ATOMIC_RELAXED, __HIP_MEMORY_SCOPE_AGENT);
        } while ((unsigned)(v >> 32) != (unsigned)t && ++guard < (1L << 14));
      }
      HP hv; hv.u = (unsigned)v;
      const int r = tid >> 6, up = tid & 63;
      const int ka = cs * 128 + up;
      *(_Float16*)((char*)hfrag + afrag_addr(ka,      r)) = hv.f[0];
      *(_Float16*)((char*)hfrag + afrag_addr(ka + 64, r)) = hv.f[1];
      __syncthreads();
    }

    // ---- sibling-half K MFMA
#pragma unroll
    for (int kx = 0; kx < 4; ++kx) {
      FU a; a.u4 = hfrag[(ksib + kx) * 64 + lane];
      acc0 = __builtin_amdgcn_mfma_f32_16x16x32_f16(a.h8, wf0[4 + kx].h8, acc0, 0, 0, 0);
      acc1 = __builtin_amdgcn_mfma_f32_16x16x32_f16(a.h8, wf1[4 + kx].h8, acc1, 0, 0, 0);
    }
    {
      const int cq = lane >> 4, cn = lane & 15;   // C: row=(lane>>4)*4+reg
#pragma unroll
      for (int reg = 0; reg < 4; ++reg) {
        zbuf[(cq * 4 + reg) * ZS + (wv * 2)     * 16 + cn] = acc0[reg];
        zbuf[(cq * 4 + reg) * ZS + (wv * 2 + 1) * 16 + cn] = acc1[reg];
      }
    }
    __syncthreads();   // zbuf ready

    // ---- gates: thread = (row wv, units u0 = c*128+lane, u1 = u0+64)
    {
      float4 z0 = *(const float4*)&zbuf[wv * ZS + lane * 4];
      float4 z1 = *(const float4*)&zbuf[wv * ZS + lane * 4 + 256];
      float i0 = sigm(z0.x + xb0.x), f0 = sigm(z0.y + xb0.y);
      float g0 = tanhx(z0.z + xb0.z), o0 = sigm(z0.w + xb0.w);
      cst0 = f0 * cst0 + i0 * g0;
      float h0 = o0 * tanhx(cst0);
      float i1 = sigm(z1.x + xb1.x), f1 = sigm(z1.y + xb1.y);
      float g1 = tanhx(z1.z + xb1.z), o1 = sigm(z1.w + xb1.w);
      cst1 = f1 * cst1 + i1 * g1;
      float h1 = o1 * tanhx(cst1);

      HP p; p.f[0] = (_Float16)h0; p.f[1] = (_Float16)h1;
      hpub = p;
      // own half straight to own-kk A-frags
      const int ka = c * 128 + lane;
      *(_Float16*)((char*)hfrag + afrag_addr(ka,      wv)) = p.f[0];
      *(_Float16*)((char*)hfrag + afrag_addr(ka + 64, wv)) = p.f[1];
      // publish tagged payload twice (fire-and-forget; self-validating):
      // fast L2-resident mirror first, then the agent-scope fallback.
      const int par1 = (t + 1) & 1;
      const int poff = ((par1 * 64 + g) * 2 + c) * 1024 + tid;
      unsigned long long val =
          ((unsigned long long)(unsigned)(t + 1) << 32) | (unsigned long long)p.u;
      __hip_atomic_store(fx2 + poff, val, __ATOMIC_RELAXED, __HIP_MEMORY_SCOPE_WORKGROUP);
      __hip_atomic_store(hx2 + poff, val, __ATOMIC_RELAXED, __HIP_MEMORY_SCOPE_AGENT);
    }
    __syncthreads();   // hfrag own-half + zbuf handoff for next iteration
  }

  if (c != 0) return;

  // ---- Epilogue (c==0): h_T -> fp32, Wd, softmax.
  // Own half (half==0) comes straight from this thread's last publish
  // (identical value, no memory round trip). Sibling half is polled with
  // the same fast->slow dual path (tag==TSTEPS, par=0).
  {
    const int r = tid >> 6, up = tid & 63;
    zbuf[r * ZS + up]      = (float)hpub.f[0];
    zbuf[r * ZS + up + 64] = (float)hpub.f[1];

    const int off = (g * 2 + 1) * 1024 + tid;
    unsigned long long v = 0;
    bool got = false;
    if (fast_ok) {
      const unsigned long long* fsrc = fx2 + off;
      for (int s = 0; s < 256; ++s) {
        v = ld_l2(fsrc);
        if ((unsigned)(v >> 32) == (unsigned)TSTEPS) { got = true; break; }
      }
    }
    if (!got) {
      const unsigned long long* src = hx2 + off;
      long guard = 0;
      do {
        v = __hip_atomic_load(src, __ATOMIC_RELAXED, __HIP_MEMORY_SCOPE_AGENT);
      } while ((unsigned)(v >> 32) != (unsigned)TSTEPS && ++guard < (1L << 14));
    }
    HP hv; hv.u = (unsigned)v;
    zbuf[r * ZS + 128 + up]      = (float)hv.f[0];
    zbuf[r * ZS + 128 + up + 64] = (float)hv.f[1];
  }
  __syncthreads();
  {
    const int j  = tid & 127;
    const int rb = tid >> 7;            // 0..7 -> rows 2rb, 2rb+1
    const int r0 = rb * 2, r1 = r0 + 1;
    float l0 = bd[j], l1 = bd[j];
    for (int k = 0; k < 256; ++k) {
      float w = Wd[k * NCHAR + j];
      l0 += zbuf[r0 * ZS + k] * w;
      l1 += zbuf[r1 * ZS + k] * w;
    }
    lgts[r0 * 132 + j] = l0;
    lgts[r1 * 132 + j] = l1;
  }
  __syncthreads();
  if (tid < 16) {
    const int r = tid;
    float m = -1e30f;
    for (int j = 0; j < NCHAR; ++j) m = fmaxf(m, lgts[r * 132 + j]);
    float s = 0.f;
    for (int j = 0; j < NCHAR; ++j) s += __expf(lgts[r * 132 + j] - m);
    rmax[r] = m;
    rsum[r] = fast_rcp(s);
  }
  __syncthreads();
  {
    const int j  = tid & 127;
    const int rb = tid >> 7;
#pragma unroll
    for (int ii = 0; ii < 2; ++ii) {
      int r = rb * 2 + ii;
      out[(row0 + r) * NCHAR + j] = __expf(lgts[r * 132 + j] - rmax[r]) * rsum[r];
    }
  }
}

extern "C" void kernel_launch(void* const* d_in, const int* in_sizes, int n_in,
                              void* d_out, int out_size, void* d_ws, size_t ws_size,
                              hipStream_t stream) {
  const int*   inp = (const int*)d_in[0];
  const float* Wx  = (const float*)d_in[1];
  const float* Wh  = (const float*)d_in[2];
  const float* bia = (const float*)d_in[3];
  const float* Wd  = (const float*)d_in[4];
  const float* bd  = (const float*)d_in[5];

  uint4*              WhB  = (uint4*)d_ws;                          // 512 KB
  float4*             Wxbg = (float4*)((char*)d_ws + (512 << 10));  // 512 KB
  unsigned long long* hx2  = (unsigned long long*)((char*)d_ws + (1 << 20)); // 2 MB (agent path)
  unsigned long long* fx2  = (unsigned long long*)((char*)d_ws + (3 << 20)); // 2 MB (L2 fast mirror)

  prep_whB<<<128, 256, 0, stream>>>(Wh, WhB);
  prep_wx<<<128, 256, 0, stream>>>(Wx, bia, Wxbg);
  lstm_mfma<<<128, 1024, 0, stream>>>(inp, WhB, Wxbg, Wd, bd, (float*)d_out,
                                      hx2, fx2);
}

// Round 2
// 1141.475 us; speedup vs baseline: 1.0199x; 1.0199x over previous
//
#include <hip/hip_runtime.h>

// LSTM char-RNN forward: batch=1024, T=512, UNITS=256, NUM_CHARS=128.
// R10 = R8 (1094us) + same-XCD L2 fast exchange, FIXED producer store.
//
// R9 post-mortem: WRITE_SIZE grew by exactly +2MB (= one writeback of the
// whole fx2 mirror) -> the workgroup-scope mirror store never reached the
// shared XCD L2 during the run (sat in a CU-local writeback cache), so the
// sibling's sc0 polls always saw stale tags, every consumer burned the
// strike-out spins (~35us one-time = the observed +70us), then ran the R8
// path. Fix: producer publishes the mirror with an explicit
// `global_store_dwordx2 ... sc0` (L1-coherent -> lands in the per-XCD L2;
// sc1=0 so it does NOT write through to HBM). Consumer polls with the
// matching sc0 load (bypass L1, read L2). Sibling blocks (g, g+64) share
// an XCD under the bid%8 round-robin (64%8==0), so when pairing holds the
// exchange round trip drops from ~1500-2000cyc (agent/HBM coherence
// point) to ~400-600cyc (L2). Fast path is self-validating (tag==t) and
// downgrades permanently after 3 missed steps (spins 128@t1 / 32 after ->
// worst-case one-time cost ~15us if pairing is wrong), falling back to
// R8's proven agent-scope path. The consumer's first fast poll is issued
// BEFORE the own-half K MFMA and its use is register-tied through the
// s_waitcnt (guide rule #18) so ~L2 latency hides under the MFMAs.
// Arithmetic identical to R8 -> same absmax (6.1e-5).

#define TSTEPS 512
#define UNITS  256
#define NCHAR  128
#define G4     1024
#define ZS     516   // zbuf row stride

typedef float    f32x4 __attribute__((ext_vector_type(4)));
typedef _Float16 f16x8 __attribute__((ext_vector_type(8)));

union FU { uint4 u4; f16x8 h8; _Float16 h[8]; };
union HP { unsigned int u; _Float16 f[2]; };

__device__ __forceinline__ float fast_rcp(float x) {
#if __has_builtin(__builtin_amdgcn_rcpf)
  return __builtin_amdgcn_rcpf(x);
#else
  return 1.0f / x;
#endif
}
__device__ __forceinline__ float sigm(float x)  { return fast_rcp(1.0f + __expf(-x)); }
__device__ __forceinline__ float tanhx(float x) { return 2.0f * fast_rcp(1.0f + __expf(-2.0f * x)) - 1.0f; }

// Consumer side: L1-bypass load, reads the shared per-XCD L2 copy.
__device__ __forceinline__ unsigned long long ld_l2(const unsigned long long* p) {
  unsigned long long v;
  asm volatile("global_load_dwordx2 %0, %1, off sc0\n\ts_waitcnt vmcnt(0)"
               : "=v"(v) : "v"(p) : "memory");
  return v;
}
// Producer side: write-through-L1 store that LANDS IN L2 (sc0, no sc1 ->
// not pushed to HBM). This is the fix over R9's workgroup-scope store,
// which lingered CU-locally and was never visible to the sibling.
__device__ __forceinline__ void st_l2(unsigned long long* p, unsigned long long v) {
  asm volatile("global_store_dwordx2 %0, %1, off sc0" :: "v"(p), "v"(v) : "memory");
}

// ---- Prep: WhB = Wh fp16 B-fragment stream. idx=((cc*32+tile)*8+kk)*64+l.
__global__ void prep_whB(const float* __restrict__ Wh, uint4* __restrict__ WhB) {
  int idx = blockIdx.x * blockDim.x + threadIdx.x;    // 0..32767
  int l    = idx & 63;
  int kk   = (idx >> 6) & 7;
  int tile = (idx >> 9) & 31;
  int cc   = idx >> 14;
  int n    = tile * 16 + (l & 15);
  int gate = n & 3;
  int col  = gate * 256 + cc * 128 + (n >> 2);
  int kb   = kk * 32 + (l >> 4) * 8;
  FU p;
#pragma unroll
  for (int j = 0; j < 8; ++j)
    p.h[j] = (_Float16)Wh[(kb + j) * G4 + col];
  WhB[idx] = p.u4;
}

// ---- Prep: Wxbg[ch][u] = float4(i,f,g,o) = Wx[ch][gate*256+u] + b
__global__ void prep_wx(const float* __restrict__ Wx, const float* __restrict__ bias,
                        float4* __restrict__ Wxbg) {
  int idx = blockIdx.x * blockDim.x + threadIdx.x;    // 0..32767
  int u  = idx & (UNITS - 1);
  int ch = idx >> 8;
  const float* r = Wx + ch * G4;
  float4 o;
  o.x = r[0 * UNITS + u] + bias[0 * UNITS + u];
  o.y = r[1 * UNITS + u] + bias[1 * UNITS + u];
  o.z = r[2 * UNITS + u] + bias[2 * UNITS + u];
  o.w = r[3 * UNITS + u] + bias[3 * UNITS + u];
  Wxbg[idx] = o;
}

// A-frag LDS byte address for h element (row m, k).
__device__ __forceinline__ int afrag_addr(int k, int m) {
  return ((k >> 5) << 10) + (((((k >> 3) & 3) << 4) + m) << 4) + ((k & 7) << 1);
}

// ---- Main: 128 blocks x 1024 threads. (g = bid&63, c = bid>>6).
__global__ __launch_bounds__(1024) void lstm_mfma(
    const int* __restrict__ inp, const uint4* __restrict__ WhB,
    const float4* __restrict__ Wxbg, const float* __restrict__ Wd,
    const float* __restrict__ bd, float* __restrict__ out,
    unsigned long long* __restrict__ hx2, unsigned long long* __restrict__ fx2) {
  __shared__ __align__(16) uint4 hfrag[512];     // 8 KB: h_t A-frags (K=256)
  __shared__ float zbuf[16 * ZS];                // 33 KB
  __shared__ float lgts[16 * 132];               // 8.4 KB
  __shared__ float rmax[16], rsum[16];

  const int tid  = threadIdx.x;
  const int lane = tid & 63;
  const int wv   = tid >> 6;          // 0..15 == batch row within group
  const int bid  = blockIdx.x;
  const int g    = bid & 63;
  const int c    = bid >> 6;          // column half
  const int row0 = g * 16;

  // ---- Weight B-frags, own-half kk's in slots 0..3, sibling-half in 4..7.
  FU wf0[8], wf1[8];
#pragma unroll
  for (int kx = 0; kx < 8; ++kx) {
    int kk = (kx < 4) ? (c * 4 + kx) : ((1 - c) * 4 + (kx - 4));
    wf0[kx].u4 = WhB[((c * 32 + wv * 2)     * 8 + kk) * 64 + lane];
    wf1[kx].u4 = WhB[((c * 32 + wv * 2 + 1) * 8 + kk) * 64 + lane];
  }
#pragma unroll
  for (int kx = 0; kx < 8; ++kx) {
    asm volatile("" : "+v"(wf0[kx].u4.x), "+v"(wf0[kx].u4.y), "+v"(wf0[kx].u4.z), "+v"(wf0[kx].u4.w));
    asm volatile("" : "+v"(wf1[kx].u4.x), "+v"(wf1[kx].u4.y), "+v"(wf1[kx].u4.z), "+v"(wf1[kx].u4.w));
  }

  if (tid < 512) hfrag[tid] = uint4{0u, 0u, 0u, 0u};   // h_0 = 0
  float cst0 = 0.f, cst1 = 0.f;
  __syncthreads();
  const int kown = c * 4, ksib = (1 - c) * 4;
  const int cs   = 1 - c;

  bool fast_ok = true;   // same-XCD heuristic; self-correcting
  int  strikes = 0;
  HP   hpub; hpub.u = 0;

  for (int t = 0; t < TSTEPS; ++t) {
    int    ch  = inp[(row0 + wv) * TSTEPS + t];
    float4 xb0 = Wxbg[ch * 256 + c * 128 + lane];
    float4 xb1 = Wxbg[ch * 256 + c * 128 + 64 + lane];

    // ---- prefetch the fast-path exchange word (hides L2 latency under
    // the own-half MFMAs below).
    const int par = t & 1;
    const int off = ((par * 64 + g) * 2 + cs) * 1024 + tid;
    const unsigned long long* fsrc = fx2 + off;
    unsigned long long vpre = 0;
    if (t > 0 && fast_ok) {
      asm volatile("global_load_dwordx2 %0, %1, off sc0" : "=v"(vpre) : "v"(fsrc));
    }

    // ---- own-half K MFMA first (hides exchange latency); t=0: hfrag = 0
    f32x4 acc0 = {0.f, 0.f, 0.f, 0.f}, acc1 = {0.f, 0.f, 0.f, 0.f};
#pragma unroll
    for (int kx = 0; kx < 4; ++kx) {
      FU a; a.u4 = hfrag[(kown + kx) * 64 + lane];
      acc0 = __builtin_amdgcn_mfma_f32_16x16x32_f16(a.h8, wf0[kx].h8, acc0, 0, 0, 0);
      acc1 = __builtin_amdgcn_mfma_f32_16x16x32_f16(a.h8, wf1[kx].h8, acc1, 0, 0, 0);
    }

    if (t > 0) {
      // ---- fused detect+gather: poll own payload word until tag == t.
      // Fast: sc0 poll of the L2-resident mirror. Slow: R8 agent path.
      unsigned long long v = 0;
      bool got = false;
      if (fast_ok) {
        // tie the prefetched value through the waitcnt (rule #18)
        asm volatile("s_waitcnt vmcnt(0)" : "+v"(vpre));
        if ((unsigned)(vpre >> 32) == (unsigned)t) { v = vpre; got = true; }
        else {
          const int spins = (t == 1) ? 128 : 32;
          for (int s = 0; s < spins; ++s) {
            v = ld_l2(fsrc);
            if ((unsigned)(v >> 32) == (unsigned)t) { got = true; break; }
          }
        }
        if (!got && ++strikes >= 3) fast_ok = false;
      }
      if (!got) {
        const unsigned long long* src = hx2 + off;
        long guard = 0;
        do {
          v = __hip_atomic_load(src, __ATOMIC_RELAXED, __HIP_MEMORY_SCOPE_AGENT);
        } while ((unsigned)(v >> 32) != (unsigned)t && ++guard < (1L << 14));
      }
      HP hv; hv.u = (unsigned)v;
      const int r = tid >> 6, up = tid & 63;
      const int ka = cs * 128 + up;
      *(_Float16*)((char*)hfrag + afrag_addr(ka,      r)) = hv.f[0];
      *(_Float16*)((char*)hfrag + afrag_addr(ka + 64, r)) = hv.f[1];
      __syncthreads();
    }

    // ---- sibling-half K MFMA
#pragma unroll
    for (int kx = 0; kx < 4; ++kx) {
      FU a; a.u4 = hfrag[(ksib + kx) * 64 + lane];
      acc0 = __builtin_amdgcn_mfma_f32_16x16x32_f16(a.h8, wf0[4 + kx].h8, acc0, 0, 0, 0);
      acc1 = __builtin_amdgcn_mfma_f32_16x16x32_f16(a.h8, wf1[4 + kx].h8, acc1, 0, 0, 0);
    }
    {
      const int cq = lane >> 4, cn = lane & 15;   // C: row=(lane>>4)*4+reg
#pragma unroll
      for (int reg = 0; reg < 4; ++reg) {
        zbuf[(cq * 4 + reg) * ZS + (wv * 2)     * 16 + cn] = acc0[reg];
        zbuf[(cq * 4 + reg) * ZS + (wv * 2 + 1) * 16 + cn] = acc1[reg];
      }
    }
    __syncthreads();   // zbuf ready

    // ---- gates: thread = (row wv, units u0 = c*128+lane, u1 = u0+64)
    {
      float4 z0 = *(const float4*)&zbuf[wv * ZS + lane * 4];
      float4 z1 = *(const float4*)&zbuf[wv * ZS + lane * 4 + 256];
      float i0 = sigm(z0.x + xb0.x), f0 = sigm(z0.y + xb0.y);
      float g0 = tanhx(z0.z + xb0.z), o0 = sigm(z0.w + xb0.w);
      cst0 = f0 * cst0 + i0 * g0;
      float h0 = o0 * tanhx(cst0);
      float i1 = sigm(z1.x + xb1.x), f1 = sigm(z1.y + xb1.y);
      float g1 = tanhx(z1.z + xb1.z), o1 = sigm(z1.w + xb1.w);
      cst1 = f1 * cst1 + i1 * g1;
      float h1 = o1 * tanhx(cst1);

      HP p; p.f[0] = (_Float16)h0; p.f[1] = (_Float16)h1;
      hpub = p;
      // own half straight to own-kk A-frags
      const int ka = c * 128 + lane;
      *(_Float16*)((char*)hfrag + afrag_addr(ka,      wv)) = p.f[0];
      *(_Float16*)((char*)hfrag + afrag_addr(ka + 64, wv)) = p.f[1];
      // publish tagged payload twice (fire-and-forget; self-validating):
      // L2-resident sc0 mirror first, then the agent-scope fallback.
      const int par1 = (t + 1) & 1;
      const int poff = ((par1 * 64 + g) * 2 + c) * 1024 + tid;
      unsigned long long val =
          ((unsigned long long)(unsigned)(t + 1) << 32) | (unsigned long long)p.u;
      st_l2(fx2 + poff, val);
      __hip_atomic_store(hx2 + poff, val, __ATOMIC_RELAXED, __HIP_MEMORY_SCOPE_AGENT);
    }
    __syncthreads();   // hfrag own-half + zbuf handoff for next iteration
  }

  if (c != 0) return;

  // ---- Epilogue (c==0): h_T -> fp32, Wd, softmax.
  // Own half comes straight from this thread's last publish (identical
  // value, no memory round trip). Sibling half: fast->slow dual path
  // (tag==TSTEPS, par=0).
  {
    const int r = tid >> 6, up = tid & 63;
    zbuf[r * ZS + up]      = (float)hpub.f[0];
    zbuf[r * ZS + up + 64] = (float)hpub.f[1];

    const int off = (g * 2 + 1) * 1024 + tid;
    unsigned long long v = 0;
    bool got = false;
    if (fast_ok) {
      const unsigned long long* fsrc = fx2 + off;
      for (int s = 0; s < 128; ++s) {
        v = ld_l2(fsrc);
        if ((unsigned)(v >> 32) == (unsigned)TSTEPS) { got = true; break; }
      }
    }
    if (!got) {
      const unsigned long long* src = hx2 + off;
      long guard = 0;
      do {
        v = __hip_atomic_load(src, __ATOMIC_RELAXED, __HIP_MEMORY_SCOPE_AGENT);
      } while ((unsigned)(v >> 32) != (unsigned)TSTEPS && ++guard < (1L << 14));
    }
    HP hv; hv.u = (unsigned)v;
    zbuf[r * ZS + 128 + up]      = (float)hv.f[0];
    zbuf[r * ZS + 128 + up + 64] = (float)hv.f[1];
  }
  __syncthreads();
  {
    const int j  = tid & 127;
    const int rb = tid >> 7;            // 0..7 -> rows 2rb, 2rb+1
    const int r0 = rb * 2, r1 = r0 + 1;
    float l0 = bd[j], l1 = bd[j];
    for (int k = 0; k < 256; ++k) {
      float w = Wd[k * NCHAR + j];
      l0 += zbuf[r0 * ZS + k] * w;
      l1 += zbuf[r1 * ZS + k] * w;
    }
    lgts[r0 * 132 + j] = l0;
    lgts[r1 * 132 + j] = l1;
  }
  __syncthreads();
  if (tid < 16) {
    const int r = tid;
    float m = -1e30f;
    for (int j = 0; j < NCHAR; ++j) m = fmaxf(m, lgts[r * 132 + j]);
    float s = 0.f;
    for (int j = 0; j < NCHAR; ++j) s += __expf(lgts[r * 132 + j] - m);
    rmax[r] = m;
    rsum[r] = fast_rcp(s);
  }
  __syncthreads();
  {
    const int j  = tid & 127;
    const int rb = tid >> 7;
#pragma unroll
    for (int ii = 0; ii < 2; ++ii) {
      int r = rb * 2 + ii;
      out[(row0 + r) * NCHAR + j] = __expf(lgts[r * 132 + j] - rmax[r]) * rsum[r];
    }
  }
}

extern "C" void kernel_launch(void* const* d_in, const int* in_sizes, int n_in,
                              void* d_out, int out_size, void* d_ws, size_t ws_size,
                              hipStream_t stream) {
  const int*   inp = (const int*)d_in[0];
  const float* Wx  = (const float*)d_in[1];
  const float* Wh  = (const float*)d_in[2];
  const float* bia = (const float*)d_in[3];
  const float* Wd  = (const float*)d_in[4];
  const float* bd  = (const float*)d_in[5];

  uint4*              WhB  = (uint4*)d_ws;                          // 512 KB
  float4*             Wxbg = (float4*)((char*)d_ws + (512 << 10));  // 512 KB
  unsigned long long* hx2  = (unsigned long long*)((char*)d_ws + (1 << 20)); // 2 MB (agent path)
  unsigned long long* fx2  = (unsigned long long*)((char*)d_ws + (3 << 20)); // 2 MB (L2 sc0 mirror)

  prep_whB<<<128, 256, 0, stream>>>(Wh, WhB);
  prep_wx<<<128, 256, 0, stream>>>(Wx, bia, Wxbg);
  lstm_mfma<<<128, 1024, 0, stream>>>(inp, WhB, Wxbg, Wd, bd, (float*)d_out,
                                      hx2, fx2);
}

// Round 3
// 898.146 us; speedup vs baseline: 1.2962x; 1.2709x over previous
//
#include <hip/hip_runtime.h>

// LSTM char-RNN forward: batch=1024, T=512, UNITS=256, NUM_CHARS=128.
// R11: 4-way unit split. 256 blocks x 512 threads (vs R8's 128x1024) so ALL
// 256 CUs are active instead of 128. Group g (16 batch rows) is computed by
// 4 blocks c=0..3, each owning 64 units (256 of the 1024 z-columns).
//
// Why: R9/R10 proved the h-exchange round trip is structural (~900cyc agent
// coherence at the IF; sc0 loads are agent-scope = BYPASS the per-XCD L2,
// so no L2 fast path exists). R8's per-step budget per SIMD on the 128
// active CUs was MFMA 1242 + VALU 1950 + exchange ~900 + barriers ~1000
// = 5129cyc. Spreading over 2x CUs halves MFMA (621) and VALU (~975) per
// SIMD; exchange/barrier structure unchanged (3 partner polls instead of 1,
// issued as 3 independent loads BEFORE the own-K MFMAs so their latency
// overlaps in one round trip). Weights: 16 B-frags/wave = 64 AGPRs, same
// as R8 -> fits the 128-combined-reg wall. Exchange keeps R8's proven
// u64 (tag32|2xfp16) parity-double-buffered agent-scope scheme verbatim
// (stale/replay-proof via tag==t equality). Arithmetic: same fp16 h, same
// per-column math; only K-chunk summation order changes (own 64-unit
// chunk first) -> absmax expected ~6e-5 as before.

#define TSTEPS 512
#define UNITS  256
#define NCHAR  128
#define G4     1024
#define ZSL    260   // zbuf row stride (256 cols + pad)

typedef float    f32x4 __attribute__((ext_vector_type(4)));
typedef _Float16 f16x8 __attribute__((ext_vector_type(8)));

union FU { uint4 u4; f16x8 h8; _Float16 h[8]; };
union HP { unsigned int u; _Float16 f[2]; };

__device__ __forceinline__ float fast_rcp(float x) {
#if __has_builtin(__builtin_amdgcn_rcpf)
  return __builtin_amdgcn_rcpf(x);
#else
  return 1.0f / x;
#endif
}
__device__ __forceinline__ float sigm(float x)  { return fast_rcp(1.0f + __expf(-x)); }
__device__ __forceinline__ float tanhx(float x) { return 2.0f * fast_rcp(1.0f + __expf(-2.0f * x)) - 1.0f; }

// ---- Prep: WhB = Wh fp16 B-fragment stream. idx=(nt*8+kk)*64+l, nt=cc*32+tile.
__global__ void prep_whB(const float* __restrict__ Wh, uint4* __restrict__ WhB) {
  int idx = blockIdx.x * blockDim.x + threadIdx.x;    // 0..32767
  int l    = idx & 63;
  int kk   = (idx >> 6) & 7;
  int tile = (idx >> 9) & 31;
  int cc   = idx >> 14;
  int n    = tile * 16 + (l & 15);
  int gate = n & 3;
  int col  = gate * 256 + cc * 128 + (n >> 2);
  int kb   = kk * 32 + (l >> 4) * 8;
  FU p;
#pragma unroll
  for (int j = 0; j < 8; ++j)
    p.h[j] = (_Float16)Wh[(kb + j) * G4 + col];
  WhB[idx] = p.u4;
}

// ---- Prep: Wxbg[ch][u] = float4(i,f,g,o) = Wx[ch][gate*256+u] + b
__global__ void prep_wx(const float* __restrict__ Wx, const float* __restrict__ bias,
                        float4* __restrict__ Wxbg) {
  int idx = blockIdx.x * blockDim.x + threadIdx.x;    // 0..32767
  int u  = idx & (UNITS - 1);
  int ch = idx >> 8;
  const float* r = Wx + ch * G4;
  float4 o;
  o.x = r[0 * UNITS + u] + bias[0 * UNITS + u];
  o.y = r[1 * UNITS + u] + bias[1 * UNITS + u];
  o.z = r[2 * UNITS + u] + bias[2 * UNITS + u];
  o.w = r[3 * UNITS + u] + bias[3 * UNITS + u];
  Wxbg[idx] = o;
}

// A-frag LDS byte address for h element (row m, k). Same layout as R8.
__device__ __forceinline__ int afrag_addr(int k, int m) {
  return ((k >> 5) << 10) + (((((k >> 3) & 3) << 4) + m) << 4) + ((k & 7) << 1);
}

// ---- Main: 256 blocks x 512 threads. g = bid&63 (group of 16 rows),
// c = bid>>6 (unit quarter: units [c*64, c*64+64)).
__global__ __launch_bounds__(512) void lstm_mfma(
    const int* __restrict__ inp, const uint4* __restrict__ WhB,
    const float4* __restrict__ Wxbg, const float* __restrict__ Wd,
    const float* __restrict__ bd, float* __restrict__ out,
    unsigned long long* __restrict__ hx) {
  __shared__ __align__(16) uint4 hfrag[512];     // 8 KB: h_t A-frags (K=256, 16 rows)
  __shared__ float zbuf[16 * ZSL];               // 16.6 KB
  __shared__ float lgts[16 * 132];               // 8.4 KB
  __shared__ float rmax[16], rsum[16];

  const int tid  = threadIdx.x;
  const int lane = tid & 63;
  const int wv   = tid >> 6;          // 0..7
  const int bid  = blockIdx.x;
  const int g    = bid & 63;
  const int c    = bid >> 6;          // unit quarter 0..3
  const int row0 = g * 16;
  const int r    = tid >> 5;          // 0..15: batch row for gates/publish
  const int u2   = tid & 31;          // unit-within-quarter (first of 2)

  // partners (the 3 other quarters)
  const int cpa = (c == 0) ? 1 : 0;
  const int cpb = (c <= 1) ? 2 : 1;
  const int cpc = (c <= 2) ? 3 : 2;

  // ---- Weight B-frags: block tiles nt = c*16 + (wv*2, wv*2+1), all 8 kk.
  // kk slot order: slots 0,1 = own K-chunk (kk = 2c, 2c+1); slots 2..7 =
  // the remaining kk ascending. (A-side read uses the same mapping.)
  FU wf0[8], wf1[8];
  const int nt0 = c * 16 + wv * 2, nt1 = nt0 + 1;
#pragma unroll
  for (int kx = 0; kx < 8; ++kx) {
    int i  = kx - 2;
    int kk = (kx < 2) ? (2 * c + kx) : ((i < 2 * c) ? i : i + 2);
    wf0[kx].u4 = WhB[(nt0 * 8 + kk) * 64 + lane];
    wf1[kx].u4 = WhB[(nt1 * 8 + kk) * 64 + lane];
  }
#pragma unroll
  for (int kx = 0; kx < 8; ++kx) {
    asm volatile("" : "+v"(wf0[kx].u4.x), "+v"(wf0[kx].u4.y), "+v"(wf0[kx].u4.z), "+v"(wf0[kx].u4.w));
    asm volatile("" : "+v"(wf1[kx].u4.x), "+v"(wf1[kx].u4.y), "+v"(wf1[kx].u4.z), "+v"(wf1[kx].u4.w));
  }

  if (tid < 512) hfrag[tid] = uint4{0u, 0u, 0u, 0u};   // h_0 = 0
  float cst0 = 0.f, cst1 = 0.f;
  unsigned lastpk = 0;

  // A-frag byte addresses: own 2 units, 3 partners x 2 units.
  const int oa0 = afrag_addr(c   * 64 + u2,      r);
  const int oa1 = afrag_addr(c   * 64 + u2 + 32, r);
  const int ga0 = afrag_addr(cpa * 64 + u2,      r);
  const int ga1 = afrag_addr(cpa * 64 + u2 + 32, r);
  const int gb0 = afrag_addr(cpb * 64 + u2,      r);
  const int gb1 = afrag_addr(cpb * 64 + u2 + 32, r);
  const int gc0 = afrag_addr(cpc * 64 + u2,      r);
  const int gc1 = afrag_addr(cpc * 64 + u2 + 32, r);
  __syncthreads();

  for (int t = 0; t < TSTEPS; ++t) {
    int    ch  = inp[(row0 + r) * TSTEPS + t];
    float4 xb0 = Wxbg[ch * 256 + c * 64 + u2];
    float4 xb1 = Wxbg[ch * 256 + c * 64 + u2 + 32];

    // ---- issue the 3 partner polls EARLY (independent loads -> one
    // overlapped agent round trip, hidden under the own-chunk MFMAs).
    unsigned long long v0 = 0, v1 = 0, v2 = 0;
    const unsigned long long* pb = hx + (((t & 1) * 64 + g) << 11) + tid;
    if (t > 0) {
      v0 = __hip_atomic_load(pb + (cpa << 9), __ATOMIC_RELAXED, __HIP_MEMORY_SCOPE_AGENT);
      v1 = __hip_atomic_load(pb + (cpb << 9), __ATOMIC_RELAXED, __HIP_MEMORY_SCOPE_AGENT);
      v2 = __hip_atomic_load(pb + (cpc << 9), __ATOMIC_RELAXED, __HIP_MEMORY_SCOPE_AGENT);
    }

    // ---- own-chunk K MFMA (kk = 2c, 2c+1); t=0: hfrag = 0
    f32x4 acc0 = {0.f, 0.f, 0.f, 0.f}, acc1 = {0.f, 0.f, 0.f, 0.f};
#pragma unroll
    for (int kx = 0; kx < 2; ++kx) {
      int kk = 2 * c + kx;
      FU a; a.u4 = hfrag[kk * 64 + lane];
      acc0 = __builtin_amdgcn_mfma_f32_16x16x32_f16(a.h8, wf0[kx].h8, acc0, 0, 0, 0);
      acc1 = __builtin_amdgcn_mfma_f32_16x16x32_f16(a.h8, wf1[kx].h8, acc1, 0, 0, 0);
    }

    if (t > 0) {
      // ---- fused detect+gather: all 3 tags must equal t (poison/stale-proof)
      long guard = 0;
      while (((((unsigned)(v0 >> 32)) ^ (unsigned)t) |
              (((unsigned)(v1 >> 32)) ^ (unsigned)t) |
              (((unsigned)(v2 >> 32)) ^ (unsigned)t)) && ++guard < (1L << 14)) {
        v0 = __hip_atomic_load(pb + (cpa << 9), __ATOMIC_RELAXED, __HIP_MEMORY_SCOPE_AGENT);
        v1 = __hip_atomic_load(pb + (cpb << 9), __ATOMIC_RELAXED, __HIP_MEMORY_SCOPE_AGENT);
        v2 = __hip_atomic_load(pb + (cpc << 9), __ATOMIC_RELAXED, __HIP_MEMORY_SCOPE_AGENT);
      }
      *(unsigned short*)((char*)hfrag + ga0) = (unsigned short)v0;
      *(unsigned short*)((char*)hfrag + ga1) = (unsigned short)(v0 >> 16);
      *(unsigned short*)((char*)hfrag + gb0) = (unsigned short)v1;
      *(unsigned short*)((char*)hfrag + gb1) = (unsigned short)(v1 >> 16);
      *(unsigned short*)((char*)hfrag + gc0) = (unsigned short)v2;
      *(unsigned short*)((char*)hfrag + gc1) = (unsigned short)(v2 >> 16);
      __syncthreads();
    }

    // ---- remaining 6 K-chunks
#pragma unroll
    for (int kx = 2; kx < 8; ++kx) {
      int i  = kx - 2;
      int kk = (i < 2 * c) ? i : i + 2;
      FU a; a.u4 = hfrag[kk * 64 + lane];
      acc0 = __builtin_amdgcn_mfma_f32_16x16x32_f16(a.h8, wf0[kx].h8, acc0, 0, 0, 0);
      acc1 = __builtin_amdgcn_mfma_f32_16x16x32_f16(a.h8, wf1[kx].h8, acc1, 0, 0, 0);
    }
    {
      const int cq = lane >> 4, cn = lane & 15;   // C: row=(lane>>4)*4+reg
#pragma unroll
      for (int reg = 0; reg < 4; ++reg) {
        zbuf[(cq * 4 + reg) * ZSL + (wv * 2)     * 16 + cn] = acc0[reg];
        zbuf[(cq * 4 + reg) * ZSL + (wv * 2 + 1) * 16 + cn] = acc1[reg];
      }
    }
    __syncthreads();   // zbuf ready

    // ---- gates: thread = (row r, units u0 = c*64+u2, u1 = u0+32)
    {
      float4 z0 = *(const float4*)&zbuf[r * ZSL + u2 * 4];
      float4 z1 = *(const float4*)&zbuf[r * ZSL + u2 * 4 + 128];
      float i0 = sigm(z0.x + xb0.x), f0 = sigm(z0.y + xb0.y);
      float g0 = tanhx(z0.z + xb0.z), o0 = sigm(z0.w + xb0.w);
      cst0 = f0 * cst0 + i0 * g0;
      float h0 = o0 * tanhx(cst0);
      float i1 = sigm(z1.x + xb1.x), f1 = sigm(z1.y + xb1.y);
      float g1 = tanhx(z1.z + xb1.z), o1 = sigm(z1.w + xb1.w);
      cst1 = f1 * cst1 + i1 * g1;
      float h1 = o1 * tanhx(cst1);

      HP p; p.f[0] = (_Float16)h0; p.f[1] = (_Float16)h1;
      lastpk = p.u;
      // own units straight to own A-frag slots
      *(unsigned short*)((char*)hfrag + oa0) = (unsigned short)p.u;
      *(unsigned short*)((char*)hfrag + oa1) = (unsigned short)(p.u >> 16);
      // publish tagged payload (fire-and-forget; self-validating)
      unsigned long long val =
          ((unsigned long long)(unsigned)(t + 1) << 32) | (unsigned long long)p.u;
      __hip_atomic_store(hx + ((((t + 1) & 1) * 64 + g) << 11) + (c << 9) + tid, val,
                         __ATOMIC_RELAXED, __HIP_MEMORY_SCOPE_AGENT);
    }
    __syncthreads();   // hfrag own-writes + zbuf handoff for next iteration
  }

  if (c != 0) return;

  // ---- Epilogue (c==0): h_T -> fp32 (16 rows x 256), Wd, softmax.
  // Own quarter from lastpk; 3 partner quarters polled (tag==TSTEPS, par=0).
  {
    HP p; p.u = lastpk;
    zbuf[r * ZSL + u2]      = (float)p.f[0];
    zbuf[r * ZSL + u2 + 32] = (float)p.f[1];

    const unsigned long long* pb = hx + ((0 * 64 + g) << 11) + tid;  // parity 0
    unsigned long long v0 = __hip_atomic_load(pb + (1 << 9), __ATOMIC_RELAXED, __HIP_MEMORY_SCOPE_AGENT);
    unsigned long long v1 = __hip_atomic_load(pb + (2 << 9), __ATOMIC_RELAXED, __HIP_MEMORY_SCOPE_AGENT);
    unsigned long long v2 = __hip_atomic_load(pb + (3 << 9), __ATOMIC_RELAXED, __HIP_MEMORY_SCOPE_AGENT);
    long guard = 0;
    while (((((unsigned)(v0 >> 32)) ^ (unsigned)TSTEPS) |
            (((unsigned)(v1 >> 32)) ^ (unsigned)TSTEPS) |
            (((unsigned)(v2 >> 32)) ^ (unsigned)TSTEPS)) && ++guard < (1L << 14)) {
      v0 = __hip_atomic_load(pb + (1 << 9), __ATOMIC_RELAXED, __HIP_MEMORY_SCOPE_AGENT);
      v1 = __hip_atomic_load(pb + (2 << 9), __ATOMIC_RELAXED, __HIP_MEMORY_SCOPE_AGENT);
      v2 = __hip_atomic_load(pb + (3 << 9), __ATOMIC_RELAXED, __HIP_MEMORY_SCOPE_AGENT);
    }
    HP q;
    q.u = (unsigned)v0;
    zbuf[r * ZSL +  64 + u2] = (float)q.f[0];
    zbuf[r * ZSL +  96 + u2] = (float)q.f[1];
    q.u = (unsigned)v1;
    zbuf[r * ZSL + 128 + u2] = (float)q.f[0];
    zbuf[r * ZSL + 160 + u2] = (float)q.f[1];
    q.u = (unsigned)v2;
    zbuf[r * ZSL + 192 + u2] = (float)q.f[0];
    zbuf[r * ZSL + 224 + u2] = (float)q.f[1];
  }
  __syncthreads();
  {
    const int j  = tid & 127;
    const int rb = tid >> 7;            // 0..3 -> rows 4rb..4rb+3
    const int r0 = rb * 4;
    float l0 = bd[j], l1 = bd[j], l2 = bd[j], l3 = bd[j];
    for (int k = 0; k < 256; ++k) {
      float w = Wd[k * NCHAR + j];
      l0 += zbuf[(r0 + 0) * ZSL + k] * w;
      l1 += zbuf[(r0 + 1) * ZSL + k] * w;
      l2 += zbuf[(r0 + 2) * ZSL + k] * w;
      l3 += zbuf[(r0 + 3) * ZSL + k] * w;
    }
    lgts[(r0 + 0) * 132 + j] = l0;
    lgts[(r0 + 1) * 132 + j] = l1;
    lgts[(r0 + 2) * 132 + j] = l2;
    lgts[(r0 + 3) * 132 + j] = l3;
  }
  __syncthreads();
  if (tid < 16) {
    const int rr = tid;
    float m = -1e30f;
    for (int j = 0; j < NCHAR; ++j) m = fmaxf(m, lgts[rr * 132 + j]);
    float s = 0.f;
    for (int j = 0; j < NCHAR; ++j) s += __expf(lgts[rr * 132 + j] - m);
    rmax[rr] = m;
    rsum[rr] = fast_rcp(s);
  }
  __syncthreads();
  {
    const int j  = tid & 127;
    const int rb = tid >> 7;
#pragma unroll
    for (int ii = 0; ii < 4; ++ii) {
      int rr = rb * 4 + ii;
      out[(row0 + rr) * NCHAR + j] = __expf(lgts[rr * 132 + j] - rmax[rr]) * rsum[rr];
    }
  }
}

extern "C" void kernel_launch(void* const* d_in, const int* in_sizes, int n_in,
                              void* d_out, int out_size, void* d_ws, size_t ws_size,
                              hipStream_t stream) {
  const int*   inp = (const int*)d_in[0];
  const float* Wx  = (const float*)d_in[1];
  const float* Wh  = (const float*)d_in[2];
  const float* bia = (const float*)d_in[3];
  const float* Wd  = (const float*)d_in[4];
  const float* bd  = (const float*)d_in[5];

  uint4*              WhB  = (uint4*)d_ws;                          // 512 KB
  float4*             Wxbg = (float4*)((char*)d_ws + (512 << 10));  // 512 KB
  unsigned long long* hx   = (unsigned long long*)((char*)d_ws + (1 << 20)); // 2 MB

  prep_whB<<<128, 256, 0, stream>>>(Wh, WhB);
  prep_wx<<<128, 256, 0, stream>>>(Wx, bia, Wxbg);
  lstm_mfma<<<256, 512, 0, stream>>>(inp, WhB, Wxbg, Wd, bd, (float*)d_out, hx);
}